// Round 1
// 181.017 us; speedup vs baseline: 1.0034x; 1.0034x over previous
//
#include <hip/hip_runtime.h>
#include <hip/hip_bf16.h>

#define B_ 2
#define S_ 2048
#define HID 1024
#define NH 16
#define DH 64
#define QKV_N (3*HID)
#define M_ROWS (B_*S_)

typedef __attribute__((ext_vector_type(8))) short short8;
typedef __attribute__((ext_vector_type(4))) short short4v;
typedef __attribute__((ext_vector_type(4))) float floatx4;
typedef unsigned int uint;

#define QSCALE 0.18033688f   // 0.125 * log2(e), folded into Q at GEMM1 epilogue

__device__ __forceinline__ short8 load8(const __hip_bfloat16* p) {
    return *(const short8*)p;
}

#if __has_builtin(__builtin_amdgcn_exp2f)
#define EXP2F(x) __builtin_amdgcn_exp2f(x)
#else
#define EXP2F(x) exp2f(x)
#endif

__device__ __forceinline__ uint pack_bf16_2(float lo, float hi) {
    uint ul = __float_as_uint(lo) + 0x8000u;
    uint uh = __float_as_uint(hi) + 0x8000u;
    return __builtin_amdgcn_perm(uh, ul, 0x07060302);
}
__device__ __forceinline__ uint pack_bf16_2_rtne(float lo, float hi) {
    uint ul = __float_as_uint(lo); ul += 0x7FFFu + ((ul >> 16) & 1u);
    uint uh = __float_as_uint(hi); uh += 0x7FFFu + ((uh >> 16) & 1u);
    return __builtin_amdgcn_perm(uh, ul, 0x07060302);
}

#define ASYNC16(gptr, lptr) \
    __builtin_amdgcn_global_load_lds((const __attribute__((address_space(1))) void*)(gptr), \
                                     (__attribute__((address_space(3))) void*)(lptr), 16, 0, 0)
#define RAW_BARRIER() asm volatile("s_barrier" ::: "memory")

// merged f32->bf16 conversion over x | w_qkv | w_out (outputs contiguous)
__global__ __launch_bounds__(256) void cvt_all(
    const float* __restrict__ x, const float* __restrict__ wq,
    const float* __restrict__ wo, __hip_bfloat16* __restrict__ out)
{
    const int n0 = M_ROWS * HID, n1 = QKV_N * HID;
    int i = (blockIdx.x * 256 + threadIdx.x) * 4;
    const float* src; int off;
    if (i < n0)           { src = x;  off = i; }
    else if (i < n0 + n1) { src = wq; off = i - n0; }
    else                  { src = wo; off = i - n0 - n1; }
    float4 v = *(const float4*)(src + off);
    uint2 r;
    r.x = pack_bf16_2_rtne(v.x, v.y);
    r.y = pack_bf16_2_rtne(v.z, v.w);
    *(uint2*)(out + i) = r;
}

// C = A * B^T, K=1024. TMB x 128 tile, BK=32, 3-stage pipeline (raw s_barrier +
// vmcnt(G), prefetch depth 2 — never drains), unrolled x3 so buffer indices and
// LDS addresses are compile-time constant. SWAPPED MFMA operands.
// MODE 1: qkv (bf16): n<1024 (Q) scaled by QSCALE; n<2048 -> C b64 stores;
//         n>=2048 (V) -> VT per-32-permuted, scalar stores.
// MODE 2: bias add, dwordx4 f32 stores.
#define BK 32
#define NITER 32
template<int MODE, int TMB>
__global__ __launch_bounds__(256, (TMB == 128) ? 3 : 4) void gemm_bt_kernel(
    const __hip_bfloat16* __restrict__ A,
    const __hip_bfloat16* __restrict__ Bw,
    const float* __restrict__ biasf,
    __hip_bfloat16* __restrict__ C,
    float* __restrict__ Cf,
    __hip_bfloat16* __restrict__ VT,
    int Mdim, int Ndim, int Kdim)
{
    constexpr int NI = TMB / 32;
    constexpr int CA = TMB / 64;
    constexpr int WAITG = 0x0F70 | (CA + 2);
    __shared__ alignas(16) __hip_bfloat16 As[3][TMB * BK];
    __shared__ alignas(16) __hip_bfloat16 Bs[3][128 * BK];

    const int tid  = threadIdx.x;
    const int wave = tid >> 6;
    const int lane = tid & 63;
    const int q = lane >> 4;
    const int r = lane & 15;
    const int m_blk = blockIdx.y * TMB;
    const int n_blk = blockIdx.x * 128;
    const int wm = (wave >> 1) * (TMB / 2);
    const int wn = (wave & 1) * 64;

    const __hip_bfloat16* Abase = A + (size_t)m_blk * Kdim;
    const __hip_bfloat16* Bbase = Bw + (size_t)n_blk * Kdim;

    floatx4 acc[NI][4];
#pragma unroll
    for (int i = 0; i < NI; i++)
#pragma unroll
        for (int j = 0; j < 4; j++) acc[i][j] = (floatx4){0.f, 0.f, 0.f, 0.f};

    auto stage = [&](int bf, int kt) {
#pragma unroll
        for (int c = 0; c < CA; c++) {
            int ch = tid + c * 256;
            ASYNC16(Abase + (size_t)(ch >> 2) * Kdim + kt + (ch & 3) * 8, &As[bf][ch * 8]);
        }
#pragma unroll
        for (int c = 0; c < 2; c++) {
            int ch = tid + c * 256;
            ASYNC16(Bbase + (size_t)(ch >> 2) * Kdim + kt + (ch & 3) * 8, &Bs[bf][ch * 8]);
        }
    };
    auto compute = [&](int bf) {
        short8 a[NI], b[4];
#pragma unroll
        for (int i = 0; i < NI; i++) a[i] = *(const short8*)&As[bf][(wm + i * 16 + r) * BK + q * 8];
#pragma unroll
        for (int j = 0; j < 4; j++) b[j] = *(const short8*)&Bs[bf][(wn + j * 16 + r) * BK + q * 8];
#pragma unroll
        for (int i = 0; i < NI; i++)
#pragma unroll
            for (int j = 0; j < 4; j++)   // SWAPPED: first operand = B -> acc[m=..+r][n=..+q*4+reg]
                acc[i][j] = __builtin_amdgcn_mfma_f32_16x16x32_bf16(b[j], a[i], acc[i][j], 0, 0, 0);
    };

    stage(0, 0);
    stage(1, BK);
#pragma unroll 3
    for (int it = 0; it < NITER - 2; it++) {
        __builtin_amdgcn_s_waitcnt(WAITG);
        RAW_BARRIER();
        stage((it + 2) % 3, (it + 2) * BK);
        compute(it % 3);
    }
    __builtin_amdgcn_s_waitcnt(WAITG);
    RAW_BARRIER();
    compute((NITER - 2) % 3);
    __builtin_amdgcn_s_waitcnt(0x0F70);
    RAW_BARRIER();
    compute((NITER - 1) % 3);

    // epilogue (swapped layout): m = m_blk+wm+i*16+r, n = n_blk+wn+j*16+q*4+reg
#pragma unroll
    for (int i = 0; i < NI; i++) {
        const int m = m_blk + wm + i * 16 + r;
#pragma unroll
        for (int j = 0; j < 4; j++) {
            const int n0 = n_blk + wn + j * 16 + q * 4;
            if (MODE == 2) {
                float4 bv = *(const float4*)&biasf[n0];
                float4 ov;
                ov.x = acc[i][j][0] + bv.x;
                ov.y = acc[i][j][1] + bv.y;
                ov.z = acc[i][j][2] + bv.z;
                ov.w = acc[i][j][3] + bv.w;
                *(float4*)&Cf[(size_t)m * Ndim + n0] = ov;
            } else if (n_blk < 2 * HID) {
                // Q region (n < 1024): fold softmax scale into Q
                float s = (n0 < HID) ? QSCALE : 1.0f;
                uint2 pk;
                pk.x = pack_bf16_2_rtne(acc[i][j][0] * s, acc[i][j][1] * s);
                pk.y = pack_bf16_2_rtne(acc[i][j][2] * s, acc[i][j][3] * s);
                *(uint2*)&C[(size_t)m * QKV_N + n0] = pk;
            } else {
                // V: per-32 permuted transpose store (scalar)
                int bidx = m >> 11;
                int srow = m & (S_ - 1);
                int c = srow & 31;
                int sp = (srow & ~31) | ((c & 15) << 1) | ((c >> 4) & 1);
#pragma unroll
                for (int reg = 0; reg < 4; reg++) {
                    int dfull = n0 + reg - 2 * HID;
                    VT[((size_t)bidx * HID + dfull) * S_ + sp] =
                        __float2bfloat16(acc[i][j][reg]);
                }
            }
        }
    }
}

// Flash attention v12: v11 structure, with the P LDS round-trip de-serialized.
// Key change vs v11: no explicit lgkmcnt(0) drain between P writes and P/V
// reads. P is per-wave LDS and same-wave DS ops execute in program order
// (AMDGPU workgroup memory model), so the ds_read of pa issued right after
// rt's own P writes observes them; the compiler inserts the minimal
// lgkmcnt(N) data-hazard wait before the consuming MFMA. V fragments are
// hoisted to the top (independent of P), and pa[0]'s LDS latency hides under
// rt1's QK MFMAs + exp2. PV MFMA cluster wrapped in s_setprio (T5).
#define KT 32
#define PPAD 40

__global__ __launch_bounds__(512, 4) void flash_kernel(
    const __hip_bfloat16* __restrict__ qkv,  // [B][S][3072], Q pre-scaled
    const __hip_bfloat16* __restrict__ VTp,  // [B][HID][S'] per-32 permuted
    __hip_bfloat16* __restrict__ O)          // [B][S][1024]
{
    __shared__ alignas(16) char smem[69632];
    __hip_bfloat16* lds_k = (__hip_bfloat16*)smem;            // [3][2][2048] 24KB
    __hip_bfloat16* lds_v = (__hip_bfloat16*)(smem + 24576);  // [3][2][2048] 24KB
    __hip_bfloat16* lds_p = (__hip_bfloat16*)(smem + 49152);  // [8][1280]    20KB

    const int tid  = threadIdx.x;
    const int wave = tid >> 6;
    const int lane = tid & 63;
    const int q = lane >> 4;
    const int r = lane & 15;
    const int ww   = wave & 3;    // q-group
    const int khid = wave >> 2;   // k-half
    const int bh = blockIdx.x;
    const int b  = bh >> 4;
    const int h  = bh & 15;
    const int s0 = blockIdx.y * 128 + ww * 32;

    const __hip_bfloat16* Qbase = qkv + (size_t)b * S_ * QKV_N + h * DH;
    const __hip_bfloat16* Kbase = Qbase + HID;
    const __hip_bfloat16* Vbase = VTp + ((size_t)b * HID + h * DH) * S_;

    // K staging: lane -> row sr = ww*8 + (lane>>3), slot lane&7, chunk slot^(sr&7)
    const int sr = ww * 8 + (lane >> 3);
    const int kcg = (lane & 7) ^ ((lane >> 3) & 7);
    const __hip_bfloat16* gK = Kbase + (size_t)(khid * 1024 + sr) * QKV_N + kcg * 8;
    const int kldso = sr * 64 + (lane & 7) * 8;
    // V staging: lane -> row vr = ww*16 + (lane>>2), slot lane&3, chunk slot^f(vr)
    const int vr = ww * 16 + (lane >> 2);
    const int fv = (vr + (vr >> 2)) & 3;
    const int vcg = (lane & 3) ^ fv;
    const __hip_bfloat16* gV = Vbase + (size_t)vr * S_ + khid * 1024 + vcg * 8;
    const int vldso = vr * 32 + (lane & 3) * 8;

    auto stage = [&](int bf, int it) {
        ASYNC16(gK + (size_t)(it * KT) * QKV_N, &lds_k[(bf * 2 + khid) * 2048 + kldso]);
        ASYNC16(gV + it * KT,                   &lds_v[(bf * 2 + khid) * 2048 + vldso]);
    };

    floatx4 o_acc[2][4];
    floatx4 l_acc[2];
#pragma unroll
    for (int rt = 0; rt < 2; rt++) {
        l_acc[rt] = (floatx4){0.f, 0.f, 0.f, 0.f};
#pragma unroll
        for (int nb = 0; nb < 4; nb++) o_acc[rt][nb] = (floatx4){0.f, 0.f, 0.f, 0.f};
    }
    short8 ones;
#pragma unroll
    for (int i = 0; i < 8; i++) ones[i] = (short)0x3F80;

    __hip_bfloat16* Pw = &lds_p[wave * 1280];

    short8 a_q[2][2];
    auto compute = [&](int bf) {
        const __hip_bfloat16* Kt = &lds_k[(bf * 2 + khid) * 2048];
        const __hip_bfloat16* Vt = &lds_v[(bf * 2 + khid) * 2048];
        // K fragments
        short8 bk[2][2];
#pragma unroll
        for (int ct = 0; ct < 2; ct++)
#pragma unroll
            for (int kh = 0; kh < 2; kh++)
                bk[ct][kh] = *(const short8*)&Kt[(ct * 16 + r) * 64 + ((kh * 4 + q) ^ (r & 7)) * 8];
        // V fragments, hoisted: independent of P, same for both rt
        short8 vb[4];
#pragma unroll
        for (int nb = 0; nb < 4; nb++) {
            int d = nb * 16 + r;
            vb[nb] = *(const short8*)&Vt[d * 32 + ((q ^ ((d + (d >> 2)) & 3)) * 8)];
        }

        // QK^T -> exp2 -> P write -> pa read, per rt. pa[rt] only needs rt's
        // own P rows (disjoint per rt), and same-wave DS is in program order,
        // so no lgkmcnt(0) drain: pa[0]'s latency hides under rt1's work.
        short8 pa[2];
#pragma unroll
        for (int rt = 0; rt < 2; rt++) {
            floatx4 sc[2];
#pragma unroll
            for (int ct = 0; ct < 2; ct++) {
                floatx4 z = (floatx4){0.f, 0.f, 0.f, 0.f};
                z = __builtin_amdgcn_mfma_f32_16x16x32_bf16(a_q[rt][0], bk[ct][0], z, 0, 0, 0);
                z = __builtin_amdgcn_mfma_f32_16x16x32_bf16(a_q[rt][1], bk[ct][1], z, 0, 0, 0);
                sc[ct] = z;
            }
            // Q pre-scaled: P = exp2(sc), unnormalized (cancels in o/l).
            // score col c = ct*16+r stored at k~ = 2r+ct (matches per-32 V perm)
#pragma unroll
            for (int reg = 0; reg < 4; reg++) {
                float e0 = EXP2F(sc[0][reg]);
                float e1 = EXP2F(sc[1][reg]);
                *(uint*)&Pw[(rt * 16 + q * 4 + reg) * PPAD + 2 * r] = pack_bf16_2(e0, e1);
            }
            pa[rt] = *(const short8*)&Pw[(rt * 16 + r) * PPAD + q * 8];
        }

        // l + PV: pure-MFMA cluster, favor on the CU scheduler (T5)
        __builtin_amdgcn_s_setprio(1);
#pragma unroll
        for (int rt = 0; rt < 2; rt++) {
            l_acc[rt] = __builtin_amdgcn_mfma_f32_16x16x32_bf16(pa[rt], ones, l_acc[rt], 0, 0, 0);
#pragma unroll
            for (int nb = 0; nb < 4; nb++)
                o_acc[rt][nb] = __builtin_amdgcn_mfma_f32_16x16x32_bf16(pa[rt], vb[nb], o_acc[rt][nb], 0, 0, 0);
        }
        __builtin_amdgcn_s_setprio(0);
    };

    // one pipelined step; bf passed as a constant at each call site
    auto step = [&](int it, int bf) {
        __builtin_amdgcn_s_waitcnt(0x0F72);  // vmcnt(2): buffer `it` staged (own wave)
        RAW_BARRIER();
        stage((bf + 2) % 3, it + 2);
        compute(bf);
    };

    // prologue: stage(0) + Q loads, drain, stage(1) in flight
    stage(0, 0);
#pragma unroll
    for (int rt = 0; rt < 2; rt++)
#pragma unroll
        for (int kh = 0; kh < 2; kh++)
            a_q[rt][kh] = load8(Qbase + (size_t)(s0 + rt * 16 + r) * QKV_N + kh * 32 + q * 8);
    __builtin_amdgcn_s_waitcnt(0x0F70);
    stage(1, 1);

    for (int itb = 0; itb < 30; itb += 3) {   // x3 unroll: bf compile-time constant
        step(itb + 0, 0);
        step(itb + 1, 1);
        step(itb + 2, 2);
    }
    __builtin_amdgcn_s_waitcnt(0x0F72);      // it=30
    RAW_BARRIER();
    compute(0);
    __builtin_amdgcn_s_waitcnt(0x0F70);      // it=31: last buffer
    RAW_BARRIER();
    compute(1);

    // combine k-halves (o,l additive). Reuse K/V LDS (post-barrier).
    __syncthreads();
    float* of = (float*)smem;             // 4 groups x 8KB = 32KB
    float* lf = (float*)(smem + 32768);   // 4 groups x 2KB = 8KB
    if (khid == 1) {
#pragma unroll
        for (int rt = 0; rt < 2; rt++) {
#pragma unroll
            for (int nb = 0; nb < 4; nb++)
                *(floatx4*)&of[ww * 2048 + (rt * 4 + nb) * 256 + lane * 4] = o_acc[rt][nb];
            *(floatx4*)&lf[ww * 512 + rt * 256 + lane * 4] = l_acc[rt];
        }
    }
    __syncthreads();
    if (khid == 0) {
#pragma unroll
        for (int rt = 0; rt < 2; rt++) {
            l_acc[rt] += *(const floatx4*)&lf[ww * 512 + rt * 256 + lane * 4];
#pragma unroll
            for (int nb = 0; nb < 4; nb++)
                o_acc[rt][nb] += *(const floatx4*)&of[ww * 2048 + (rt * 4 + nb) * 256 + lane * 4];
        }
#pragma unroll
        for (int rt = 0; rt < 2; rt++) {
#pragma unroll
            for (int reg = 0; reg < 4; reg++) {
                float inv = 1.f / l_acc[rt][reg];
                int srow2 = s0 + rt * 16 + q * 4 + reg;
                __hip_bfloat16* Orow = O + ((size_t)b * S_ + srow2) * HID + h * DH;
#pragma unroll
                for (int nb = 0; nb < 4; nb++)
                    Orow[nb * 16 + r] = __float2bfloat16(o_acc[rt][nb][reg] * inv);
            }
        }
    }
}

extern "C" void kernel_launch(void* const* d_in, const int* in_sizes, int n_in,
                              void* d_out, int out_size, void* d_ws, size_t ws_size,
                              hipStream_t stream) {
    const float* x_f     = (const float*)d_in[0];
    const float* w_qkv_f = (const float*)d_in[1];
    const float* w_out_f = (const float*)d_in[2];
    const float* b_out_f = (const float*)d_in[3];
    float* out = (float*)d_out;

    __hip_bfloat16* xb      = (__hip_bfloat16*)d_ws;
    __hip_bfloat16* wqkvb   = xb    + (size_t)M_ROWS * HID;
    __hip_bfloat16* woutb   = wqkvb + (size_t)QKV_N * HID;
    __hip_bfloat16* qkv_ws  = woutb + (size_t)HID * HID;
    __hip_bfloat16* vt_ws   = qkv_ws + (size_t)M_ROWS * QKV_N;
    __hip_bfloat16* attn_ws = vt_ws + (size_t)B_ * HID * S_;

    dim3 blk(256);
    {
        int ntot = M_ROWS * HID + QKV_N * HID + HID * HID;
        cvt_all<<<dim3(ntot / 1024), blk, 0, stream>>>(x_f, w_qkv_f, w_out_f, xb);
    }

    gemm_bt_kernel<1, 128><<<dim3(QKV_N / 128, M_ROWS / 128), blk, 0, stream>>>(
        xb, wqkvb, nullptr, qkv_ws, nullptr, vt_ws, M_ROWS, QKV_N, HID);
    flash_kernel<<<dim3(B_ * NH, S_ / 128), dim3(512), 0, stream>>>(qkv_ws, vt_ws, attn_ws);
    gemm_bt_kernel<2, 64><<<dim3(HID / 128, M_ROWS / 64), blk, 0, stream>>>(
        attn_ws, woutb, b_out_f, nullptr, out, nullptr, M_ROWS, HID, HID);
}

// Round 2
// 181.017 us; speedup vs baseline: 1.0034x; 1.0000x over previous
//
#include <hip/hip_runtime.h>
#include <hip/hip_bf16.h>

#define B_ 2
#define S_ 2048
#define HID 1024
#define NH 16
#define DH 64
#define QKV_N (3*HID)
#define M_ROWS (B_*S_)

typedef __attribute__((ext_vector_type(8))) short short8;
typedef __attribute__((ext_vector_type(4))) short short4v;
typedef __attribute__((ext_vector_type(4))) float floatx4;
typedef __attribute__((ext_vector_type(4))) unsigned int uint4v;
typedef unsigned int uint;

#define QSCALE 0.18033688f   // 0.125 * log2(e), folded into Q at GEMM1 epilogue

__device__ __forceinline__ short8 load8(const __hip_bfloat16* p) {
    return *(const short8*)p;
}

#if __has_builtin(__builtin_amdgcn_exp2f)
#define EXP2F(x) __builtin_amdgcn_exp2f(x)
#else
#define EXP2F(x) exp2f(x)
#endif

__device__ __forceinline__ uint pack_bf16_2(float lo, float hi) {
    uint ul = __float_as_uint(lo) + 0x8000u;
    uint uh = __float_as_uint(hi) + 0x8000u;
    return __builtin_amdgcn_perm(uh, ul, 0x07060302);
}
__device__ __forceinline__ uint pack_bf16_2_rtne(float lo, float hi) {
    uint ul = __float_as_uint(lo); ul += 0x7FFFu + ((ul >> 16) & 1u);
    uint uh = __float_as_uint(hi); uh += 0x7FFFu + ((uh >> 16) & 1u);
    return __builtin_amdgcn_perm(uh, ul, 0x07060302);
}

#define ASYNC16(gptr, lptr) \
    __builtin_amdgcn_global_load_lds((const __attribute__((address_space(1))) void*)(gptr), \
                                     (__attribute__((address_space(3))) void*)(lptr), 16, 0, 0)
#define RAW_BARRIER() asm volatile("s_barrier" ::: "memory")

// merged f32->bf16 conversion over x | w_qkv | w_out (outputs contiguous)
__global__ __launch_bounds__(256) void cvt_all(
    const float* __restrict__ x, const float* __restrict__ wq,
    const float* __restrict__ wo, __hip_bfloat16* __restrict__ out)
{
    const int n0 = M_ROWS * HID, n1 = QKV_N * HID;
    int i = (blockIdx.x * 256 + threadIdx.x) * 4;
    const float* src; int off;
    if (i < n0)           { src = x;  off = i; }
    else if (i < n0 + n1) { src = wq; off = i - n0; }
    else                  { src = wo; off = i - n0 - n1; }
    float4 v = *(const float4*)(src + off);
    uint2 r;
    r.x = pack_bf16_2_rtne(v.x, v.y);
    r.y = pack_bf16_2_rtne(v.z, v.w);
    *(uint2*)(out + i) = r;
}

// C = A * B^T, K=1024. TMB x 128 tile, BK=32, 3-stage pipeline (raw s_barrier +
// vmcnt(G), prefetch depth 2 — never drains), unrolled x3 so buffer indices and
// LDS addresses are compile-time constant. SWAPPED MFMA operands.
// MODE 1: qkv (bf16): n<1024 (Q) scaled by QSCALE; n<2048 -> C b64 stores;
//         n>=2048 (V) -> VT NATURAL transpose, scalar stores (flash consumes
//         natural k-order now — no per-32 permute).
// MODE 2: bias add, dwordx4 f32 stores.
#define BK 32
#define NITER 32
template<int MODE, int TMB>
__global__ __launch_bounds__(256, (TMB == 128) ? 3 : 4) void gemm_bt_kernel(
    const __hip_bfloat16* __restrict__ A,
    const __hip_bfloat16* __restrict__ Bw,
    const float* __restrict__ biasf,
    __hip_bfloat16* __restrict__ C,
    float* __restrict__ Cf,
    __hip_bfloat16* __restrict__ VT,
    int Mdim, int Ndim, int Kdim)
{
    constexpr int NI = TMB / 32;
    constexpr int CA = TMB / 64;
    constexpr int WAITG = 0x0F70 | (CA + 2);
    __shared__ alignas(16) __hip_bfloat16 As[3][TMB * BK];
    __shared__ alignas(16) __hip_bfloat16 Bs[3][128 * BK];

    const int tid  = threadIdx.x;
    const int wave = tid >> 6;
    const int lane = tid & 63;
    const int q = lane >> 4;
    const int r = lane & 15;
    const int m_blk = blockIdx.y * TMB;
    const int n_blk = blockIdx.x * 128;
    const int wm = (wave >> 1) * (TMB / 2);
    const int wn = (wave & 1) * 64;

    const __hip_bfloat16* Abase = A + (size_t)m_blk * Kdim;
    const __hip_bfloat16* Bbase = Bw + (size_t)n_blk * Kdim;

    floatx4 acc[NI][4];
#pragma unroll
    for (int i = 0; i < NI; i++)
#pragma unroll
        for (int j = 0; j < 4; j++) acc[i][j] = (floatx4){0.f, 0.f, 0.f, 0.f};

    auto stage = [&](int bf, int kt) {
#pragma unroll
        for (int c = 0; c < CA; c++) {
            int ch = tid + c * 256;
            ASYNC16(Abase + (size_t)(ch >> 2) * Kdim + kt + (ch & 3) * 8, &As[bf][ch * 8]);
        }
#pragma unroll
        for (int c = 0; c < 2; c++) {
            int ch = tid + c * 256;
            ASYNC16(Bbase + (size_t)(ch >> 2) * Kdim + kt + (ch & 3) * 8, &Bs[bf][ch * 8]);
        }
    };
    auto compute = [&](int bf) {
        short8 a[NI], b[4];
#pragma unroll
        for (int i = 0; i < NI; i++) a[i] = *(const short8*)&As[bf][(wm + i * 16 + r) * BK + q * 8];
#pragma unroll
        for (int j = 0; j < 4; j++) b[j] = *(const short8*)&Bs[bf][(wn + j * 16 + r) * BK + q * 8];
#pragma unroll
        for (int i = 0; i < NI; i++)
#pragma unroll
            for (int j = 0; j < 4; j++)   // SWAPPED: first operand = B -> acc[m=..+r][n=..+q*4+reg]
                acc[i][j] = __builtin_amdgcn_mfma_f32_16x16x32_bf16(b[j], a[i], acc[i][j], 0, 0, 0);
    };

    stage(0, 0);
    stage(1, BK);
#pragma unroll 3
    for (int it = 0; it < NITER - 2; it++) {
        __builtin_amdgcn_s_waitcnt(WAITG);
        RAW_BARRIER();
        stage((it + 2) % 3, (it + 2) * BK);
        compute(it % 3);
    }
    __builtin_amdgcn_s_waitcnt(WAITG);
    RAW_BARRIER();
    compute((NITER - 2) % 3);
    __builtin_amdgcn_s_waitcnt(0x0F70);
    RAW_BARRIER();
    compute((NITER - 1) % 3);

    // epilogue (swapped layout): m = m_blk+wm+i*16+r, n = n_blk+wn+j*16+q*4+reg
#pragma unroll
    for (int i = 0; i < NI; i++) {
        const int m = m_blk + wm + i * 16 + r;
#pragma unroll
        for (int j = 0; j < 4; j++) {
            const int n0 = n_blk + wn + j * 16 + q * 4;
            if (MODE == 2) {
                float4 bv = *(const float4*)&biasf[n0];
                float4 ov;
                ov.x = acc[i][j][0] + bv.x;
                ov.y = acc[i][j][1] + bv.y;
                ov.z = acc[i][j][2] + bv.z;
                ov.w = acc[i][j][3] + bv.w;
                *(float4*)&Cf[(size_t)m * Ndim + n0] = ov;
            } else if (n_blk < 2 * HID) {
                // Q region (n < 1024): fold softmax scale into Q
                float s = (n0 < HID) ? QSCALE : 1.0f;
                uint2 pk;
                pk.x = pack_bf16_2_rtne(acc[i][j][0] * s, acc[i][j][1] * s);
                pk.y = pack_bf16_2_rtne(acc[i][j][2] * s, acc[i][j][3] * s);
                *(uint2*)&C[(size_t)m * QKV_N + n0] = pk;
            } else {
                // V: natural transpose store (scalar, 16 consecutive srow per line)
                int bidx = m >> 11;
                int srow = m & (S_ - 1);
#pragma unroll
                for (int reg = 0; reg < 4; reg++) {
                    int dfull = n0 + reg - 2 * HID;
                    VT[((size_t)bidx * HID + dfull) * S_ + srow] =
                        __float2bfloat16(acc[i][j][reg]);
                }
            }
        }
    }
}

// Flash attention v13: ZERO-SHUFFLE P path. Swapped QK^T (mfma(K,Q)) puts
// P[qrow=r][k = ct*16+q*4+reg] directly in each lane — a valid A-fragment
// under the k-slot permutation pi(q,j) = (j>>2)*16 + q*4 + (j&3). V is read
// with the SAME pi (two ds_read_b64 per fragment instead of one b128), so
// the MFMA contraction is order-consistent and P never touches LDS: the
// 8 ds_write + 2 ds_read round-trip per iteration (and its bank conflicts
// and latency) is gone. VT is consumed in natural s-order (gemm1 stores it
// unpermuted). O/l accumulator layout is unchanged (first-operand fragment
// rows are still r), so the combine epilogue is untouched. LDS: 48KB.
#define KT 32

__global__ __launch_bounds__(512, 4) void flash_kernel(
    const __hip_bfloat16* __restrict__ qkv,  // [B][S][3072], Q pre-scaled
    const __hip_bfloat16* __restrict__ VTp,  // [B][HID][S] natural transpose
    __hip_bfloat16* __restrict__ O)          // [B][S][1024]
{
    __shared__ alignas(16) char smem[49152];
    __hip_bfloat16* lds_k = (__hip_bfloat16*)smem;            // [3][2][2048] 24KB
    __hip_bfloat16* lds_v = (__hip_bfloat16*)(smem + 24576);  // [3][2][2048] 24KB

    const int tid  = threadIdx.x;
    const int wave = tid >> 6;
    const int lane = tid & 63;
    const int q = lane >> 4;
    const int r = lane & 15;
    const int ww   = wave & 3;    // q-group
    const int khid = wave >> 2;   // k-half
    const int bh = blockIdx.x;
    const int b  = bh >> 4;
    const int h  = bh & 15;
    const int s0 = blockIdx.y * 128 + ww * 32;

    const __hip_bfloat16* Qbase = qkv + (size_t)b * S_ * QKV_N + h * DH;
    const __hip_bfloat16* Kbase = Qbase + HID;
    const __hip_bfloat16* Vbase = VTp + ((size_t)b * HID + h * DH) * S_;

    // K staging: lane -> row sr = ww*8 + (lane>>3), slot lane&7, chunk slot^(sr&7)
    const int sr = ww * 8 + (lane >> 3);
    const int kcg = (lane & 7) ^ ((lane >> 3) & 7);
    const __hip_bfloat16* gK = Kbase + (size_t)(khid * 1024 + sr) * QKV_N + kcg * 8;
    const int kldso = sr * 64 + (lane & 7) * 8;
    // V staging: lane -> row vr = ww*16 + (lane>>2), octet lane&3, global octet = (lane&3)^fv
    const int vr = ww * 16 + (lane >> 2);
    const int fv = (vr + (vr >> 2)) & 3;
    const int vcg = (lane & 3) ^ fv;
    const __hip_bfloat16* gV = Vbase + (size_t)vr * S_ + khid * 1024 + vcg * 8;
    const int vldso = vr * 32 + (lane & 3) * 8;

    auto stage = [&](int bf, int it) {
        ASYNC16(gK + (size_t)(it * KT) * QKV_N, &lds_k[(bf * 2 + khid) * 2048 + kldso]);
        ASYNC16(gV + it * KT,                   &lds_v[(bf * 2 + khid) * 2048 + vldso]);
    };

    floatx4 o_acc[2][4];
    floatx4 l_acc[2];
#pragma unroll
    for (int rt = 0; rt < 2; rt++) {
        l_acc[rt] = (floatx4){0.f, 0.f, 0.f, 0.f};
#pragma unroll
        for (int nb = 0; nb < 4; nb++) o_acc[rt][nb] = (floatx4){0.f, 0.f, 0.f, 0.f};
    }
    short8 ones;
#pragma unroll
    for (int i = 0; i < 8; i++) ones[i] = (short)0x3F80;

    short8 a_q[2][2];
    auto compute = [&](int bf) {
        const __hip_bfloat16* Kt = &lds_k[(bf * 2 + khid) * 2048];
        const __hip_bfloat16* Vt = &lds_v[(bf * 2 + khid) * 2048];
        // K fragments
        short8 bk[2][2];
#pragma unroll
        for (int ct = 0; ct < 2; ct++)
#pragma unroll
            for (int kh = 0; kh < 2; kh++)
                bk[ct][kh] = *(const short8*)&Kt[(ct * 16 + r) * 64 + ((kh * 4 + q) ^ (r & 7)) * 8];
        // V fragments under pi: slot j -> s = (j>>2)*16 + q*4 + (j&3).
        // Two b64 reads (octet (q>>1) and (q>>1)+2, each at within-octet (q&1)*4),
        // un-xored by the staging swizzle fv(d).
        short8 vb[4];
#pragma unroll
        for (int nb = 0; nb < 4; nb++) {
            int d = nb * 16 + r;
            int fvd = (d + (d >> 2)) & 3;
            short4v lo = *(const short4v*)&Vt[d * 32 + (((q >> 1) ^ fvd) * 8 + (q & 1) * 4)];
            short4v hi = *(const short4v*)&Vt[d * 32 + ((((q >> 1) + 2) ^ fvd) * 8 + (q & 1) * 4)];
            vb[nb] = __builtin_shufflevector(lo, hi, 0, 1, 2, 3, 4, 5, 6, 7);
        }

#pragma unroll
        for (int rt = 0; rt < 2; rt++) {
            floatx4 sc[2];
#pragma unroll
            for (int ct = 0; ct < 2; ct++) {
                floatx4 z = (floatx4){0.f, 0.f, 0.f, 0.f};
                // SWAPPED: first operand = K -> D[k-col = q*4+reg][qrow = r]
                z = __builtin_amdgcn_mfma_f32_16x16x32_bf16(bk[ct][0], a_q[rt][0], z, 0, 0, 0);
                z = __builtin_amdgcn_mfma_f32_16x16x32_bf16(bk[ct][1], a_q[rt][1], z, 0, 0, 0);
                sc[ct] = z;
            }
            // lane holds P[qrow=r][k = ct*16+q*4+reg]: exactly A-frag slots under pi.
            // Q pre-scaled: P = exp2(sc), unnormalized (cancels in o/l).
            uint4v up;
            up.x = pack_bf16_2(EXP2F(sc[0][0]), EXP2F(sc[0][1]));
            up.y = pack_bf16_2(EXP2F(sc[0][2]), EXP2F(sc[0][3]));
            up.z = pack_bf16_2(EXP2F(sc[1][0]), EXP2F(sc[1][1]));
            up.w = pack_bf16_2(EXP2F(sc[1][2]), EXP2F(sc[1][3]));
            short8 pa = __builtin_bit_cast(short8, up);

            __builtin_amdgcn_s_setprio(1);
            l_acc[rt] = __builtin_amdgcn_mfma_f32_16x16x32_bf16(pa, ones, l_acc[rt], 0, 0, 0);
#pragma unroll
            for (int nb = 0; nb < 4; nb++)
                o_acc[rt][nb] = __builtin_amdgcn_mfma_f32_16x16x32_bf16(pa, vb[nb], o_acc[rt][nb], 0, 0, 0);
            __builtin_amdgcn_s_setprio(0);
        }
    };

    // one pipelined step; bf passed as a constant at each call site
    auto step = [&](int it, int bf) {
        __builtin_amdgcn_s_waitcnt(0x0F72);  // vmcnt(2): buffer `it` staged (own wave)
        RAW_BARRIER();
        stage((bf + 2) % 3, it + 2);
        compute(bf);
    };

    // prologue: stage(0) + Q loads, drain, stage(1) in flight
    stage(0, 0);
#pragma unroll
    for (int rt = 0; rt < 2; rt++)
#pragma unroll
        for (int kh = 0; kh < 2; kh++)
            a_q[rt][kh] = load8(Qbase + (size_t)(s0 + rt * 16 + r) * QKV_N + kh * 32 + q * 8);
    __builtin_amdgcn_s_waitcnt(0x0F70);
    stage(1, 1);

    for (int itb = 0; itb < 30; itb += 3) {   // x3 unroll: bf compile-time constant
        step(itb + 0, 0);
        step(itb + 1, 1);
        step(itb + 2, 2);
    }
    __builtin_amdgcn_s_waitcnt(0x0F72);      // it=30
    RAW_BARRIER();
    compute(0);
    __builtin_amdgcn_s_waitcnt(0x0F70);      // it=31: last buffer
    RAW_BARRIER();
    compute(1);

    // combine k-halves (o,l additive). Reuse K/V LDS (post-barrier).
    __syncthreads();
    float* of = (float*)smem;             // 4 groups x 8KB = 32KB
    float* lf = (float*)(smem + 32768);   // 4 groups x 2KB = 8KB
    if (khid == 1) {
#pragma unroll
        for (int rt = 0; rt < 2; rt++) {
#pragma unroll
            for (int nb = 0; nb < 4; nb++)
                *(floatx4*)&of[ww * 2048 + (rt * 4 + nb) * 256 + lane * 4] = o_acc[rt][nb];
            *(floatx4*)&lf[ww * 512 + rt * 256 + lane * 4] = l_acc[rt];
        }
    }
    __syncthreads();
    if (khid == 0) {
#pragma unroll
        for (int rt = 0; rt < 2; rt++) {
            l_acc[rt] += *(const floatx4*)&lf[ww * 512 + rt * 256 + lane * 4];
#pragma unroll
            for (int nb = 0; nb < 4; nb++)
                o_acc[rt][nb] += *(const floatx4*)&of[ww * 2048 + (rt * 4 + nb) * 256 + lane * 4];
        }
#pragma unroll
        for (int rt = 0; rt < 2; rt++) {
#pragma unroll
            for (int reg = 0; reg < 4; reg++) {
                float inv = 1.f / l_acc[rt][reg];
                int srow2 = s0 + rt * 16 + q * 4 + reg;
                __hip_bfloat16* Orow = O + ((size_t)b * S_ + srow2) * HID + h * DH;
#pragma unroll
                for (int nb = 0; nb < 4; nb++)
                    Orow[nb * 16 + r] = __float2bfloat16(o_acc[rt][nb][reg] * inv);
            }
        }
    }
}

extern "C" void kernel_launch(void* const* d_in, const int* in_sizes, int n_in,
                              void* d_out, int out_size, void* d_ws, size_t ws_size,
                              hipStream_t stream) {
    const float* x_f     = (const float*)d_in[0];
    const float* w_qkv_f = (const float*)d_in[1];
    const float* w_out_f = (const float*)d_in[2];
    const float* b_out_f = (const float*)d_in[3];
    float* out = (float*)d_out;

    __hip_bfloat16* xb      = (__hip_bfloat16*)d_ws;
    __hip_bfloat16* wqkvb   = xb    + (size_t)M_ROWS * HID;
    __hip_bfloat16* woutb   = wqkvb + (size_t)QKV_N * HID;
    __hip_bfloat16* qkv_ws  = woutb + (size_t)HID * HID;
    __hip_bfloat16* vt_ws   = qkv_ws + (size_t)M_ROWS * QKV_N;
    __hip_bfloat16* attn_ws = vt_ws + (size_t)B_ * HID * S_;

    dim3 blk(256);
    {
        int ntot = M_ROWS * HID + QKV_N * HID + HID * HID;
        cvt_all<<<dim3(ntot / 1024), blk, 0, stream>>>(x_f, w_qkv_f, w_out_f, xb);
    }

    gemm_bt_kernel<1, 128><<<dim3(QKV_N / 128, M_ROWS / 128), blk, 0, stream>>>(
        xb, wqkvb, nullptr, qkv_ws, nullptr, vt_ws, M_ROWS, QKV_N, HID);
    flash_kernel<<<dim3(B_ * NH, S_ / 128), dim3(512), 0, stream>>>(qkv_ws, vt_ws, attn_ws);
    gemm_bt_kernel<2, 64><<<dim3(HID / 128, M_ROWS / 64), blk, 0, stream>>>(
        attn_ws, woutb, b_out_f, nullptr, out, nullptr, M_ROWS, HID, HID);
}

// Round 3
// 173.259 us; speedup vs baseline: 1.0483x; 1.0448x over previous
//
#include <hip/hip_runtime.h>
#include <hip/hip_bf16.h>

#define B_ 2
#define S_ 2048
#define HID 1024
#define NH 16
#define DH 64
#define QKV_N (3*HID)
#define M_ROWS (B_*S_)

typedef __attribute__((ext_vector_type(8))) short short8;
typedef __attribute__((ext_vector_type(4))) short short4v;
typedef __attribute__((ext_vector_type(4))) float floatx4;
typedef __attribute__((ext_vector_type(4))) unsigned int uint4v;
typedef unsigned int uint;

#define QSCALE 0.18033688f   // 0.125 * log2(e), folded into Q at GEMM1 epilogue

__device__ __forceinline__ short8 load8(const __hip_bfloat16* p) {
    return *(const short8*)p;
}

#if __has_builtin(__builtin_amdgcn_exp2f)
#define EXP2F(x) __builtin_amdgcn_exp2f(x)
#else
#define EXP2F(x) exp2f(x)
#endif

__device__ __forceinline__ uint pack_bf16_2(float lo, float hi) {
    uint ul = __float_as_uint(lo) + 0x8000u;
    uint uh = __float_as_uint(hi) + 0x8000u;
    return __builtin_amdgcn_perm(uh, ul, 0x07060302);
}
__device__ __forceinline__ uint pack_bf16_2_rtne(float lo, float hi) {
    uint ul = __float_as_uint(lo); ul += 0x7FFFu + ((ul >> 16) & 1u);
    uint uh = __float_as_uint(hi); uh += 0x7FFFu + ((uh >> 16) & 1u);
    return __builtin_amdgcn_perm(uh, ul, 0x07060302);
}

#define ASYNC16(gptr, lptr) \
    __builtin_amdgcn_global_load_lds((const __attribute__((address_space(1))) void*)(gptr), \
                                     (__attribute__((address_space(3))) void*)(lptr), 16, 0, 0)
#define RAW_BARRIER() asm volatile("s_barrier" ::: "memory")

// merged f32->bf16 conversion over x | w_qkv | w_out (outputs contiguous)
__global__ __launch_bounds__(256) void cvt_all(
    const float* __restrict__ x, const float* __restrict__ wq,
    const float* __restrict__ wo, __hip_bfloat16* __restrict__ out)
{
    const int n0 = M_ROWS * HID, n1 = QKV_N * HID;
    int i = (blockIdx.x * 256 + threadIdx.x) * 4;
    const float* src; int off;
    if (i < n0)           { src = x;  off = i; }
    else if (i < n0 + n1) { src = wq; off = i - n0; }
    else                  { src = wo; off = i - n0 - n1; }
    float4 v = *(const float4*)(src + off);
    uint2 r;
    r.x = pack_bf16_2_rtne(v.x, v.y);
    r.y = pack_bf16_2_rtne(v.z, v.w);
    *(uint2*)(out + i) = r;
}

// C = A * B^T, K=1024. TMB x 128 tile, BK=32, 3-stage pipeline (raw s_barrier +
// vmcnt(G), prefetch depth 2 — never drains), unrolled x3 so buffer indices and
// LDS addresses are compile-time constant. SWAPPED MFMA operands.
// MODE 1: qkv (bf16): n<1024 (Q) scaled by QSCALE; n<2048 -> C b64 stores;
//         n>=2048 (V) -> VT transpose with per-32 s-permutation
//         p(c) = ((c>>2)&3)*8 + (c>>4)*4 + (c&3), matching flash's
//         zero-shuffle P k-order pi(q,j) so V reads stay single b128.
// MODE 2: bias add, dwordx4 f32 stores.
#define BK 32
#define NITER 32
template<int MODE, int TMB>
__global__ __launch_bounds__(256, (TMB == 128) ? 3 : 4) void gemm_bt_kernel(
    const __hip_bfloat16* __restrict__ A,
    const __hip_bfloat16* __restrict__ Bw,
    const float* __restrict__ biasf,
    __hip_bfloat16* __restrict__ C,
    float* __restrict__ Cf,
    __hip_bfloat16* __restrict__ VT,
    int Mdim, int Ndim, int Kdim)
{
    constexpr int NI = TMB / 32;
    constexpr int CA = TMB / 64;
    constexpr int WAITG = 0x0F70 | (CA + 2);
    __shared__ alignas(16) __hip_bfloat16 As[3][TMB * BK];
    __shared__ alignas(16) __hip_bfloat16 Bs[3][128 * BK];

    const int tid  = threadIdx.x;
    const int wave = tid >> 6;
    const int lane = tid & 63;
    const int q = lane >> 4;
    const int r = lane & 15;
    const int m_blk = blockIdx.y * TMB;
    const int n_blk = blockIdx.x * 128;
    const int wm = (wave >> 1) * (TMB / 2);
    const int wn = (wave & 1) * 64;

    const __hip_bfloat16* Abase = A + (size_t)m_blk * Kdim;
    const __hip_bfloat16* Bbase = Bw + (size_t)n_blk * Kdim;

    floatx4 acc[NI][4];
#pragma unroll
    for (int i = 0; i < NI; i++)
#pragma unroll
        for (int j = 0; j < 4; j++) acc[i][j] = (floatx4){0.f, 0.f, 0.f, 0.f};

    auto stage = [&](int bf, int kt) {
#pragma unroll
        for (int c = 0; c < CA; c++) {
            int ch = tid + c * 256;
            ASYNC16(Abase + (size_t)(ch >> 2) * Kdim + kt + (ch & 3) * 8, &As[bf][ch * 8]);
        }
#pragma unroll
        for (int c = 0; c < 2; c++) {
            int ch = tid + c * 256;
            ASYNC16(Bbase + (size_t)(ch >> 2) * Kdim + kt + (ch & 3) * 8, &Bs[bf][ch * 8]);
        }
    };
    auto compute = [&](int bf) {
        short8 a[NI], b[4];
#pragma unroll
        for (int i = 0; i < NI; i++) a[i] = *(const short8*)&As[bf][(wm + i * 16 + r) * BK + q * 8];
#pragma unroll
        for (int j = 0; j < 4; j++) b[j] = *(const short8*)&Bs[bf][(wn + j * 16 + r) * BK + q * 8];
#pragma unroll
        for (int i = 0; i < NI; i++)
#pragma unroll
            for (int j = 0; j < 4; j++)   // SWAPPED: first operand = B -> acc[m=..+r][n=..+q*4+reg]
                acc[i][j] = __builtin_amdgcn_mfma_f32_16x16x32_bf16(b[j], a[i], acc[i][j], 0, 0, 0);
    };

    stage(0, 0);
    stage(1, BK);
#pragma unroll 3
    for (int it = 0; it < NITER - 2; it++) {
        __builtin_amdgcn_s_waitcnt(WAITG);
        RAW_BARRIER();
        stage((it + 2) % 3, (it + 2) * BK);
        compute(it % 3);
    }
    __builtin_amdgcn_s_waitcnt(WAITG);
    RAW_BARRIER();
    compute((NITER - 2) % 3);
    __builtin_amdgcn_s_waitcnt(0x0F70);
    RAW_BARRIER();
    compute((NITER - 1) % 3);

    // epilogue (swapped layout): m = m_blk+wm+i*16+r, n = n_blk+wn+j*16+q*4+reg
#pragma unroll
    for (int i = 0; i < NI; i++) {
        const int m = m_blk + wm + i * 16 + r;
#pragma unroll
        for (int j = 0; j < 4; j++) {
            const int n0 = n_blk + wn + j * 16 + q * 4;
            if (MODE == 2) {
                float4 bv = *(const float4*)&biasf[n0];
                float4 ov;
                ov.x = acc[i][j][0] + bv.x;
                ov.y = acc[i][j][1] + bv.y;
                ov.z = acc[i][j][2] + bv.z;
                ov.w = acc[i][j][3] + bv.w;
                *(float4*)&Cf[(size_t)m * Ndim + n0] = ov;
            } else if (n_blk < 2 * HID) {
                // Q region (n < 1024): fold softmax scale into Q
                float s = (n0 < HID) ? QSCALE : 1.0f;
                uint2 pk;
                pk.x = pack_bf16_2_rtne(acc[i][j][0] * s, acc[i][j][1] * s);
                pk.y = pack_bf16_2_rtne(acc[i][j][2] * s, acc[i][j][3] * s);
                *(uint2*)&C[(size_t)m * QKV_N + n0] = pk;
            } else {
                // V: transpose store with per-32 s-permutation
                // p(c) = ((c>>2)&3)*8 + ((c>>4)&1)*4 + (c&3)  (bijective)
                int bidx = m >> 11;
                int srow = m & (S_ - 1);
                int c = srow & 31;
                int sp = (srow & ~31) | (((c >> 2) & 3) << 3) | (((c >> 4) & 1) << 2) | (c & 3);
#pragma unroll
                for (int reg = 0; reg < 4; reg++) {
                    int dfull = n0 + reg - 2 * HID;
                    VT[((size_t)bidx * HID + dfull) * S_ + sp] =
                        __float2bfloat16(acc[i][j][reg]);
                }
            }
        }
    }
}

// Flash attention v14: zero-shuffle P (v13) + single-b128 V reads (v11 geometry).
// Swapped QK^T (mfma(K,Q)) puts P[qrow=r][k = ct*16+q*4+reg] in registers — a
// valid A-fragment under the k-slot permutation pi(q,j) = (j>>2)*16+q*4+(j&3).
// P never touches LDS. V is stored (gemm1) with the per-32 s-permutation p(c)
// matching pi, so each lane's 8 needed V elements are CONTIGUOUS: one
// ds_read_b128 at octet q (xor staging swizzle), uniform 8-accesses/bank
// across the wave — conflict-free. O/l layouts unchanged; epilogue untouched.
#define KT 32

__global__ __launch_bounds__(512, 4) void flash_kernel(
    const __hip_bfloat16* __restrict__ qkv,  // [B][S][3072], Q pre-scaled
    const __hip_bfloat16* __restrict__ VTp,  // [B][HID][S] per-32 p-permuted
    __hip_bfloat16* __restrict__ O)          // [B][S][1024]
{
    __shared__ alignas(16) char smem[49152];
    __hip_bfloat16* lds_k = (__hip_bfloat16*)smem;            // [3][2][2048] 24KB
    __hip_bfloat16* lds_v = (__hip_bfloat16*)(smem + 24576);  // [3][2][2048] 24KB

    const int tid  = threadIdx.x;
    const int wave = tid >> 6;
    const int lane = tid & 63;
    const int q = lane >> 4;
    const int r = lane & 15;
    const int ww   = wave & 3;    // q-group
    const int khid = wave >> 2;   // k-half
    const int bh = blockIdx.x;
    const int b  = bh >> 4;
    const int h  = bh & 15;
    const int s0 = blockIdx.y * 128 + ww * 32;

    const __hip_bfloat16* Qbase = qkv + (size_t)b * S_ * QKV_N + h * DH;
    const __hip_bfloat16* Kbase = Qbase + HID;
    const __hip_bfloat16* Vbase = VTp + ((size_t)b * HID + h * DH) * S_;

    // K staging: lane -> row sr = ww*8 + (lane>>3), slot lane&7, chunk slot^(sr&7)
    const int sr = ww * 8 + (lane >> 3);
    const int kcg = (lane & 7) ^ ((lane >> 3) & 7);
    const __hip_bfloat16* gK = Kbase + (size_t)(khid * 1024 + sr) * QKV_N + kcg * 8;
    const int kldso = sr * 64 + (lane & 7) * 8;
    // V staging: lane -> row vr = ww*16 + (lane>>2), octet lane&3, global octet = (lane&3)^fv
    const int vr = ww * 16 + (lane >> 2);
    const int fv = (vr + (vr >> 2)) & 3;
    const int vcg = (lane & 3) ^ fv;
    const __hip_bfloat16* gV = Vbase + (size_t)vr * S_ + khid * 1024 + vcg * 8;
    const int vldso = vr * 32 + (lane & 3) * 8;

    auto stage = [&](int bf, int it) {
        ASYNC16(gK + (size_t)(it * KT) * QKV_N, &lds_k[(bf * 2 + khid) * 2048 + kldso]);
        ASYNC16(gV + it * KT,                   &lds_v[(bf * 2 + khid) * 2048 + vldso]);
    };

    floatx4 o_acc[2][4];
    floatx4 l_acc[2];
#pragma unroll
    for (int rt = 0; rt < 2; rt++) {
        l_acc[rt] = (floatx4){0.f, 0.f, 0.f, 0.f};
#pragma unroll
        for (int nb = 0; nb < 4; nb++) o_acc[rt][nb] = (floatx4){0.f, 0.f, 0.f, 0.f};
    }
    short8 ones;
#pragma unroll
    for (int i = 0; i < 8; i++) ones[i] = (short)0x3F80;

    short8 a_q[2][2];
    auto compute = [&](int bf) {
        const __hip_bfloat16* Kt = &lds_k[(bf * 2 + khid) * 2048];
        const __hip_bfloat16* Vt = &lds_v[(bf * 2 + khid) * 2048];
        // K fragments
        short8 bk[2][2];
#pragma unroll
        for (int ct = 0; ct < 2; ct++)
#pragma unroll
            for (int kh = 0; kh < 2; kh++)
                bk[ct][kh] = *(const short8*)&Kt[(ct * 16 + r) * 64 + ((kh * 4 + q) ^ (r & 7)) * 8];
        // V fragments: single b128 at octet q (un-xored by staging swizzle).
        // LDS octet holds VT positions q*8..q*8+7 = s-values pi(q, 0..7).
        short8 vb[4];
#pragma unroll
        for (int nb = 0; nb < 4; nb++) {
            int d = nb * 16 + r;
            vb[nb] = *(const short8*)&Vt[d * 32 + ((q ^ ((d + (d >> 2)) & 3)) * 8)];
        }

#pragma unroll
        for (int rt = 0; rt < 2; rt++) {
            floatx4 sc[2];
#pragma unroll
            for (int ct = 0; ct < 2; ct++) {
                floatx4 z = (floatx4){0.f, 0.f, 0.f, 0.f};
                // SWAPPED: first operand = K -> D[k-col = q*4+reg][qrow = r]
                z = __builtin_amdgcn_mfma_f32_16x16x32_bf16(bk[ct][0], a_q[rt][0], z, 0, 0, 0);
                z = __builtin_amdgcn_mfma_f32_16x16x32_bf16(bk[ct][1], a_q[rt][1], z, 0, 0, 0);
                sc[ct] = z;
            }
            // lane holds P[qrow=r][k = ct*16+q*4+reg]: A-frag slots under pi.
            // Q pre-scaled: P = exp2(sc), unnormalized (cancels in o/l).
            uint4v up;
            up.x = pack_bf16_2(EXP2F(sc[0][0]), EXP2F(sc[0][1]));
            up.y = pack_bf16_2(EXP2F(sc[0][2]), EXP2F(sc[0][3]));
            up.z = pack_bf16_2(EXP2F(sc[1][0]), EXP2F(sc[1][1]));
            up.w = pack_bf16_2(EXP2F(sc[1][2]), EXP2F(sc[1][3]));
            short8 pa = __builtin_bit_cast(short8, up);

            __builtin_amdgcn_s_setprio(1);
            l_acc[rt] = __builtin_amdgcn_mfma_f32_16x16x32_bf16(pa, ones, l_acc[rt], 0, 0, 0);
#pragma unroll
            for (int nb = 0; nb < 4; nb++)
                o_acc[rt][nb] = __builtin_amdgcn_mfma_f32_16x16x32_bf16(pa, vb[nb], o_acc[rt][nb], 0, 0, 0);
            __builtin_amdgcn_s_setprio(0);
        }
    };

    // one pipelined step; bf passed as a constant at each call site
    auto step = [&](int it, int bf) {
        __builtin_amdgcn_s_waitcnt(0x0F72);  // vmcnt(2): buffer `it` staged (own wave)
        RAW_BARRIER();
        stage((bf + 2) % 3, it + 2);
        compute(bf);
    };

    // prologue: stage(0) + Q loads, drain, stage(1) in flight
    stage(0, 0);
#pragma unroll
    for (int rt = 0; rt < 2; rt++)
#pragma unroll
        for (int kh = 0; kh < 2; kh++)
            a_q[rt][kh] = load8(Qbase + (size_t)(s0 + rt * 16 + r) * QKV_N + kh * 32 + q * 8);
    __builtin_amdgcn_s_waitcnt(0x0F70);
    stage(1, 1);

    for (int itb = 0; itb < 30; itb += 3) {   // x3 unroll: bf compile-time constant
        step(itb + 0, 0);
        step(itb + 1, 1);
        step(itb + 2, 2);
    }
    __builtin_amdgcn_s_waitcnt(0x0F72);      // it=30
    RAW_BARRIER();
    compute(0);
    __builtin_amdgcn_s_waitcnt(0x0F70);      // it=31: last buffer
    RAW_BARRIER();
    compute(1);

    // combine k-halves (o,l additive). Reuse K/V LDS (post-barrier).
    __syncthreads();
    float* of = (float*)smem;             // 4 groups x 8KB = 32KB
    float* lf = (float*)(smem + 32768);   // 4 groups x 2KB = 8KB
    if (khid == 1) {
#pragma unroll
        for (int rt = 0; rt < 2; rt++) {
#pragma unroll
            for (int nb = 0; nb < 4; nb++)
                *(floatx4*)&of[ww * 2048 + (rt * 4 + nb) * 256 + lane * 4] = o_acc[rt][nb];
            *(floatx4*)&lf[ww * 512 + rt * 256 + lane * 4] = l_acc[rt];
        }
    }
    __syncthreads();
    if (khid == 0) {
#pragma unroll
        for (int rt = 0; rt < 2; rt++) {
            l_acc[rt] += *(const floatx4*)&lf[ww * 512 + rt * 256 + lane * 4];
#pragma unroll
            for (int nb = 0; nb < 4; nb++)
                o_acc[rt][nb] += *(const floatx4*)&of[ww * 2048 + (rt * 4 + nb) * 256 + lane * 4];
        }
#pragma unroll
        for (int rt = 0; rt < 2; rt++) {
#pragma unroll
            for (int reg = 0; reg < 4; reg++) {
                float inv = 1.f / l_acc[rt][reg];
                int srow2 = s0 + rt * 16 + q * 4 + reg;
                __hip_bfloat16* Orow = O + ((size_t)b * S_ + srow2) * HID + h * DH;
#pragma unroll
                for (int nb = 0; nb < 4; nb++)
                    Orow[nb * 16 + r] = __float2bfloat16(o_acc[rt][nb][reg] * inv);
            }
        }
    }
}

extern "C" void kernel_launch(void* const* d_in, const int* in_sizes, int n_in,
                              void* d_out, int out_size, void* d_ws, size_t ws_size,
                              hipStream_t stream) {
    const float* x_f     = (const float*)d_in[0];
    const float* w_qkv_f = (const float*)d_in[1];
    const float* w_out_f = (const float*)d_in[2];
    const float* b_out_f = (const float*)d_in[3];
    float* out = (float*)d_out;

    __hip_bfloat16* xb      = (__hip_bfloat16*)d_ws;
    __hip_bfloat16* wqkvb   = xb    + (size_t)M_ROWS * HID;
    __hip_bfloat16* woutb   = wqkvb + (size_t)QKV_N * HID;
    __hip_bfloat16* qkv_ws  = woutb + (size_t)HID * HID;
    __hip_bfloat16* vt_ws   = qkv_ws + (size_t)M_ROWS * QKV_N;
    __hip_bfloat16* attn_ws = vt_ws + (size_t)B_ * HID * S_;

    dim3 blk(256);
    {
        int ntot = M_ROWS * HID + QKV_N * HID + HID * HID;
        cvt_all<<<dim3(ntot / 1024), blk, 0, stream>>>(x_f, w_qkv_f, w_out_f, xb);
    }

    gemm_bt_kernel<1, 128><<<dim3(QKV_N / 128, M_ROWS / 128), blk, 0, stream>>>(
        xb, wqkvb, nullptr, qkv_ws, nullptr, vt_ws, M_ROWS, QKV_N, HID);
    flash_kernel<<<dim3(B_ * NH, S_ / 128), dim3(512), 0, stream>>>(qkv_ws, vt_ws, attn_ws);
    gemm_bt_kernel<2, 64><<<dim3(HID / 128, M_ROWS / 64), blk, 0, stream>>>(
        attn_ws, woutb, b_out_f, nullptr, out, nullptr, M_ROWS, HID, HID);
}